// Round 15
// baseline (538.437 us; speedup 1.0000x reference)
//
#include <hip/hip_runtime.h>
#include <hip/hip_bf16.h>

typedef __hip_bfloat16 bf16;

#define ALPHA 0.2f
#define NEGV  -9.0e15f
#define TI 8

__device__ __forceinline__ float b2f(bf16 x){ return __bfloat162float(x); }
__device__ __forceinline__ bf16  f2b(float x){ return __float2bfloat16(x); }
__device__ __forceinline__ float lrelu(float x){ return x > 0.f ? x : ALPHA*x; }
__device__ __forceinline__ float eluf(float x){ return x > 0.f ? x : expm1f(x); }

// ---------------- params block offsets (f32 elements) ----------------------
#define P_ATOMS_MASK 0
#define P_AMINO_MASK 8192
#define P_E_ATOM     24576
#define P_E_AMINO    37376
#define P_W_GAT      41216
#define P_A_GAT      73984
#define P_W_GO       74496
#define P_A_GO       107264
#define P_W_COMP_W   107520
#define P_W_COMP_B   123904
#define P_CONV_W     124032
#define P_CONV_B     124395
#define P_W_ATT_W    124398
#define P_W_ATT_B    140782
#define P_PRED_W     140910
#define P_PRED_B     141166
#define P_TOTAL      141167

__device__ __forceinline__ int detect_f32(const unsigned short* u, int n)
{
    int lim = n < 64 ? n : 64;
    bool f32like = false;
    for (int i = 0; i < lim; i += 2) {
        unsigned short h = u[i];
        int e = (h >> 7) & 0xFF;
        bool z = (h & 0x7FFF) == 0;
        if (!(z || (e >= 0x66 && e <= 0x88))) f32like = true;
    }
    if (!f32like && lim > 1 && (u[0] & 0x7FFF) == 0 && (u[1] & 0x7FFF) != 0)
        f32like = true;
    return f32like ? 1 : 0;
}
__device__ __forceinline__ float cvt_elem(const void* src, int e, int mode)
{
    return mode ? ((const float*)src)[e] : b2f(((const bf16*)src)[e]);
}

// Convert params[0..107520) (8 tensors).
__global__ __launch_bounds__(256) void k_prep_a(
    const void* p0, const void* p1, const void* p2, const void* p3,
    const void* p4, const void* p5, const void* p6, const void* p7,
    float* __restrict__ params)
{
    const void* ps[8] = {p0,p1,p2,p3,p4,p5,p6,p7};
    const int offs[9] = {0,8192,24576,37376,41216,73984,74496,107264,107520};
    int idx = blockIdx.x*256 + threadIdx.x;
    if (idx >= 107520) return;
    int k = 0;
    while (idx >= offs[k+1]) ++k;
    int mode = detect_f32((const unsigned short*)ps[k], offs[k+1]-offs[k]);
    params[idx] = cvt_elem(ps[k], idx - offs[k], mode);
}

// Convert params[107520..141167) (8 tensors).
__global__ __launch_bounds__(256) void k_prep_b(
    const void* p0, const void* p1, const void* p2, const void* p3,
    const void* p4, const void* p5, const void* p6, const void* p7,
    float* __restrict__ params)
{
    const void* ps[8] = {p0,p1,p2,p3,p4,p5,p6,p7};
    const int offs[9] = {107520,123904,124032,124395,124398,140782,140910,141166,P_TOTAL};
    int idx = blockIdx.x*256 + threadIdx.x + 107520;
    if (idx >= P_TOTAL) return;
    int k = 0;
    while (idx >= offs[k+1]) ++k;
    int mode = detect_f32((const unsigned short*)ps[k], offs[k+1]-offs[k]);
    params[idx] = cvt_elem(ps[k], idx - offs[k], mode);
}

// ---------------------------------------------------------------------------
// GAT layer 1 pre, 8 rows/block: av[k][r] in LDS; one W-load feeds 8 FMAs.
__global__ __launch_bounds__(256) void k_gat1_pre_b(
    const int* __restrict__ atoms, const float* __restrict__ params,
    bf16* __restrict__ Wh1, float* __restrict__ src1, float* __restrict__ dst1)
{
    int bid = blockIdx.x;              // b*64 + t
    int b = bid >> 6, n0 = (bid & 63) * 8;
    int tid = threadIdx.x;
    __shared__ float av[128][8];       // [k][r]
    __shared__ int aidx[8];
    if (tid < 8) aidx[tid] = atoms[b*512 + n0 + tid];
    __syncthreads();
    for (int idx = tid; idx < 1024; idx += 256) {
        int k = idx >> 3, r = idx & 7;
        av[k][r] = params[P_E_ATOM + aidx[r]*128 + k];
    }
    __syncthreads();
    int h = tid >> 6, f = tid & 63;
    const float* Wp = params + P_W_GAT + h*8192 + f;     // W_gat[h][k][f]
    float acc[8];
    #pragma unroll
    for (int r = 0; r < 8; ++r) acc[r] = 0.f;
    for (int k = 0; k < 128; ++k) {
        float w = Wp[k*64];
        #pragma unroll
        for (int r = 0; r < 8; ++r) acc[r] += av[k][r] * w;
    }
    float a1 = params[P_A_GAT + h*128 + f];
    float a2 = params[P_A_GAT + h*128 + 64 + f];
    #pragma unroll
    for (int r = 0; r < 8; ++r) {
        int n = n0 + r;
        Wh1[(size_t)(b*512 + n)*256 + h*64 + f] = f2b(acc[r]);
        float p1 = acc[r] * a1;
        float p2 = acc[r] * a2;
        #pragma unroll
        for (int m = 32; m; m >>= 1) { p1 += __shfl_xor(p1, m, 64); p2 += __shfl_xor(p2, m, 64); }
        if (f == 0) { src1[(b*4+h)*512 + n] = p1; dst1[(b*4+h)*512 + n] = p2; }
    }
}

// ---------------------------------------------------------------------------
// GAT layer 1 attention, 4 heads x TI=8 query rows per block.
__global__ __launch_bounds__(256) void k_gat1_att_b(
    const int* __restrict__ adj, const bf16* __restrict__ Wh1,
    const float* __restrict__ src1, const float* __restrict__ dst1,
    bf16* __restrict__ multi)
{
    int bid = blockIdx.x;              // b*64 + it
    int b = bid >> 6, i0 = (bid & 63) * TI;
    int tid = threadIdx.x;
    int h = tid >> 6, lane = tid & 63;
    __shared__ float att[4][TI][512];  // 64 KB
    const float* dstp = dst1 + (b*4+h)*512;
    float invr[TI];
    #pragma unroll
    for (int ti = 0; ti < TI; ++ti) {
        int i = i0 + ti;
        const int* adjrow = adj + ((size_t)(b*512 + i))*512;
        float s_i = src1[(b*4+h)*512 + i];
        float e[8];
        float lm = -3.0e38f;
        #pragma unroll
        for (int jj = 0; jj < 8; ++jj) {
            int j = lane + jj*64;
            float v = lrelu(s_i + dstp[j]);
            v = adjrow[j] > 0 ? v : NEGV;
            e[jj] = v;
            lm = fmaxf(lm, v);
        }
        #pragma unroll
        for (int m = 32; m; m >>= 1) lm = fmaxf(lm, __shfl_xor(lm, m, 64));
        float ls = 0.f;
        #pragma unroll
        for (int jj = 0; jj < 8; ++jj) {
            float ex = __expf(e[jj] - lm);
            att[h][ti][lane + jj*64] = ex;
            ls += ex;
        }
        #pragma unroll
        for (int m = 32; m; m >>= 1) ls += __shfl_xor(ls, m, 64);
        invr[ti] = 1.f / ls;
    }
    const bf16* Whp = Wh1 + (size_t)(b*512)*256 + h*64 + lane;
    float acc[TI];
    #pragma unroll
    for (int ti = 0; ti < TI; ++ti) acc[ti] = 0.f;
    for (int j = 0; j < 512; ++j) {
        float w = b2f(Whp[(size_t)j*256]);
        #pragma unroll
        for (int ti = 0; ti < TI; ++ti)
            acc[ti] += att[h][ti][j] * w;
    }
    #pragma unroll
    for (int ti = 0; ti < TI; ++ti) {
        float hp = acc[ti] * invr[ti];
        multi[(size_t)(b*512 + i0 + ti)*256 + h*64 + lane] = f2b(eluf(hp));
    }
}

// ---------------------------------------------------------------------------
// GAT layer 2 pre, 8 rows/block: row[k][r] in LDS; W_go read once per block.
__global__ __launch_bounds__(128) void k_gat2_pre_b(
    const bf16* __restrict__ multi, const float* __restrict__ params,
    bf16* __restrict__ Wh2, float* __restrict__ src2, float* __restrict__ dst2)
{
    int bid = blockIdx.x;              // b*64 + t
    int b = bid >> 6, n0 = (bid & 63) * 8;
    int tid = threadIdx.x;
    __shared__ float row[256][8];      // [k][r]
    __shared__ float sr[2][2][8];
    for (int idx = tid; idx < 2048; idx += 128) {
        int k = idx >> 3, r = idx & 7;
        row[k][r] = b2f(multi[(size_t)(b*512 + n0 + r)*256 + k]);
    }
    __syncthreads();
    const float* Wp = params + P_W_GO;
    float acc[8];
    #pragma unroll
    for (int r = 0; r < 8; ++r) acc[r] = 0.f;
    for (int k = 0; k < 256; ++k) {
        float w = Wp[k*128 + tid];
        #pragma unroll
        for (int r = 0; r < 8; ++r) acc[r] += row[k][r] * w;
    }
    float a1 = params[P_A_GO + tid];
    float a2 = params[P_A_GO + 128 + tid];
    int wid = tid >> 6;
    #pragma unroll
    for (int r = 0; r < 8; ++r) {
        Wh2[(size_t)(b*512 + n0 + r)*128 + tid] = f2b(acc[r]);
        float p1 = acc[r] * a1;
        float p2 = acc[r] * a2;
        #pragma unroll
        for (int m = 32; m; m >>= 1) { p1 += __shfl_xor(p1, m, 64); p2 += __shfl_xor(p2, m, 64); }
        if ((tid & 63) == 0) { sr[wid][0][r] = p1; sr[wid][1][r] = p2; }
    }
    __syncthreads();
    if (tid < 8)              src2[b*512 + n0 + tid]       = sr[0][0][tid] + sr[1][0][tid];
    else if (tid < 16)        dst2[b*512 + n0 + (tid-8)]   = sr[0][1][tid-8] + sr[1][1][tid-8];
}

// ---------------------------------------------------------------------------
// GAT layer 2 attention, TI=8 rows per block.
__global__ __launch_bounds__(256) void k_gat2_att_b(
    const int* __restrict__ adj, const bf16* __restrict__ Wh2,
    const float* __restrict__ src2, const float* __restrict__ dst2,
    bf16* __restrict__ x)
{
    int bid = blockIdx.x;              // b*64 + it
    int b = bid >> 6, i0 = (bid & 63) * TI;
    int tid = threadIdx.x;
    int wv = tid >> 6, lane = tid & 63;
    __shared__ float att[TI][512];
    __shared__ float red[TI][256];
    __shared__ float invs[TI];
    const float* dstp = dst2 + b*512;
    for (int ti = wv; ti < TI; ti += 4) {
        int i = i0 + ti;
        const int* adjrow = adj + ((size_t)(b*512 + i))*512;
        float s_i = src2[b*512 + i];
        float e[8];
        float lm = -3.0e38f;
        #pragma unroll
        for (int jj = 0; jj < 8; ++jj) {
            int j = lane + jj*64;
            float v = lrelu(s_i + dstp[j]);
            v = adjrow[j] > 0 ? v : NEGV;
            e[jj] = v;
            lm = fmaxf(lm, v);
        }
        #pragma unroll
        for (int m = 32; m; m >>= 1) lm = fmaxf(lm, __shfl_xor(lm, m, 64));
        float ls = 0.f;
        #pragma unroll
        for (int jj = 0; jj < 8; ++jj) {
            float ex = __expf(e[jj] - lm);
            att[ti][lane + jj*64] = ex;
            ls += ex;
        }
        #pragma unroll
        for (int m = 32; m; m >>= 1) ls += __shfl_xor(ls, m, 64);
        if (lane == 0) invs[ti] = 1.f / ls;
    }
    __syncthreads();
    int f = tid & 127, c = tid >> 7;
    const bf16* Whp = Wh2 + (size_t)(b*512)*128 + f;
    float acc[TI];
    #pragma unroll
    for (int ti = 0; ti < TI; ++ti) acc[ti] = 0.f;
    int j0 = c * 256;
    for (int j = j0; j < j0 + 256; ++j) {
        float w = b2f(Whp[(size_t)j*128]);
        #pragma unroll
        for (int ti = 0; ti < TI; ++ti)
            acc[ti] += att[ti][j] * w;
    }
    #pragma unroll
    for (int ti = 0; ti < TI; ++ti) red[ti][tid] = acc[ti];
    __syncthreads();
    if (c == 0) {
        #pragma unroll
        for (int ti = 0; ti < TI; ++ti) {
            float hp = (red[ti][f] + red[ti][f+128]) * invs[ti];
            x[(size_t)(b*512 + i0 + ti)*128 + f] = f2b(eluf(hp));
        }
    }
}

// ---------------------------------------------------------------------------
// Tiled row-matvec: out[r][l] = lrelu(in[r][:] . W[l][:] + bias[l]).
#define RM_ROWS 32
__global__ __launch_bounds__(256) void k_rowmat_tile(
    const bf16* __restrict__ in, const float* __restrict__ W,
    const float* __restrict__ bias, bf16* __restrict__ outv)
{
    __shared__ float wlds[128*129];
    __shared__ float rlds[RM_ROWS][128];
    int tid = threadIdx.x;
    size_t row0 = (size_t)blockIdx.x * RM_ROWS;
    for (int idx = tid; idx < 16384; idx += 256)
        wlds[(idx >> 7)*129 + (idx & 127)] = W[idx];
    for (int idx = tid; idx < RM_ROWS*128; idx += 256)
        rlds[idx >> 7][idx & 127] = b2f(in[row0*128 + idx]);
    __syncthreads();
    int l = tid & 127, g = tid >> 7;
    float bl = bias[l];
    #pragma unroll
    for (int rg = 0; rg < 16; rg += 4) {
        int r0 = 2*rg + g;
        float a0=0.f, a1=0.f, a2=0.f, a3=0.f;
        for (int k = 0; k < 128; ++k) {
            float w = wlds[l*129 + k];
            a0 += rlds[r0][k]*w;   a1 += rlds[r0+2][k]*w;
            a2 += rlds[r0+4][k]*w; a3 += rlds[r0+6][k]*w;
        }
        outv[(row0 + r0  )*128 + l] = f2b(lrelu(a0+bl));
        outv[(row0 + r0+2)*128 + l] = f2b(lrelu(a1+bl));
        outv[(row0 + r0+4)*128 + l] = f2b(lrelu(a2+bl));
        outv[(row0 + r0+6)*128 + l] = f2b(lrelu(a3+bl));
    }
}

// ---------------------------------------------------------------------------
// Tiled masked att-pool; one atomicAdd per l per block.
__global__ __launch_bounds__(256) void k_att_acc_tile(
    const bf16* __restrict__ in, const float* __restrict__ W,
    const float* __restrict__ bias, const float* __restrict__ mask,
    float* __restrict__ acc, int per_b)
{
    __shared__ float wlds[128*129];
    __shared__ float rlds[RM_ROWS][128];
    __shared__ float mlds[RM_ROWS];
    __shared__ float psum[128];
    int tid = threadIdx.x;
    size_t row0 = (size_t)blockIdx.x * RM_ROWS;
    int b = (int)(row0 / per_b);
    for (int idx = tid; idx < 16384; idx += 256)
        wlds[(idx >> 7)*129 + (idx & 127)] = W[idx];
    for (int idx = tid; idx < RM_ROWS*128; idx += 256)
        rlds[idx >> 7][idx & 127] = b2f(in[row0*128 + idx]);
    if (tid < RM_ROWS) mlds[tid] = mask[row0 + tid];
    __syncthreads();
    int l = tid & 127, g = tid >> 7;
    float bl = bias[l];
    float vsum = 0.f;
    #pragma unroll
    for (int rg = 0; rg < 16; rg += 4) {
        int r0 = 2*rg + g;
        float a0=0.f, a1=0.f, a2=0.f, a3=0.f;
        for (int k = 0; k < 128; ++k) {
            float w = wlds[l*129 + k];
            a0 += rlds[r0][k]*w;   a1 += rlds[r0+2][k]*w;
            a2 += rlds[r0+4][k]*w; a3 += rlds[r0+6][k]*w;
        }
        vsum += lrelu(a0+bl)*mlds[r0]   + lrelu(a1+bl)*mlds[r0+2]
              + lrelu(a2+bl)*mlds[r0+4] + lrelu(a3+bl)*mlds[r0+6];
    }
    if (g == 1) psum[l] = vsum;
    __syncthreads();
    if (g == 0) atomicAdd(&acc[b*128 + l], vsum + psum[l]);
}

// ---------------------------------------------------------------------------
// 11x11 SAME conv, 8 output rows per block (tile 18x138 staged once).
__global__ __launch_bounds__(256) void k_conv_b(
    const bf16* __restrict__ in, const int* __restrict__ amino,
    const float* __restrict__ params, bf16* __restrict__ out,
    int layer, int first)
{
    int bid = blockIdx.x;              // b*128 + t
    int b = bid >> 7, i0 = (bid & 127) * 8;
    int tid = threadIdx.x;
    __shared__ float tile[18][139];
    __shared__ float wts[121];
    __shared__ float bias;
    __shared__ int amn[18];
    if (tid < 121) wts[tid] = params[P_CONV_W + layer*121 + tid];
    if (tid == 121) bias = params[P_CONV_B + layer];
    if (first && tid < 18) {
        int ri = i0 + tid - 5;
        amn[tid] = (ri >= 0 && ri < 1024) ? amino[b*1024 + ri] : 0;
    }
    __syncthreads();
    for (int idx = tid; idx < 18*138; idx += 256) {
        int r = idx / 138, cc = idx % 138;
        int ri = i0 + r - 5, cj = cc - 5;
        float v = 0.f;
        if (ri >= 0 && ri < 1024 && cj >= 0 && cj < 128) {
            v = first ? params[P_E_AMINO + amn[r]*128 + cj]
                      : b2f(in[((size_t)(b*1024 + ri))*128 + cj]);
        }
        tile[r][cc] = v;
    }
    __syncthreads();
    int c = tid & 127, g = tid >> 7;
    #pragma unroll
    for (int rg = 0; rg < 4; ++rg) {
        int ro = rg*2 + g;
        float a = bias;
        #pragma unroll
        for (int di = 0; di < 11; ++di)
            #pragma unroll
            for (int dj = 0; dj < 11; ++dj)
                a += tile[ro + di][c + dj] * wts[di*11 + dj];
        out[(size_t)(b*1024 + i0 + ro)*128 + c] = f2b(fmaxf(a, 0.f));
    }
}

// ---------------------------------------------------------------------------
// final: mask means, leaky x2, pred dot.  block per b.  OUTPUT IS FLOAT32.
__global__ __launch_bounds__(256) void k_final(
    const float* __restrict__ params, const float* __restrict__ acc,
    float* __restrict__ out)
{
    int b = blockIdx.x, tid = threadIdx.x;
    __shared__ float red[256];
    float s = 0.f;
    for (int t = tid; t < 512; t += 256) s += params[P_ATOMS_MASK + b*512 + t];
    #pragma unroll
    for (int m = 32; m; m >>= 1) s += __shfl_xor(s, m, 64);
    if ((tid & 63) == 0) red[tid >> 6] = s;
    __syncthreads();
    float sum_atoms = red[0]+red[1]+red[2]+red[3];
    __syncthreads();
    s = 0.f;
    for (int t = tid; t < 1024; t += 256) s += params[P_AMINO_MASK + b*1024 + t];
    #pragma unroll
    for (int m = 32; m; m >>= 1) s += __shfl_xor(s, m, 64);
    if ((tid & 63) == 0) red[tid >> 6] = s;
    __syncthreads();
    float sum_amino = red[0]+red[1]+red[2]+red[3];
    __syncthreads();
    float val = (tid < 128) ? acc[b*128 + tid] / sum_atoms
                            : acc[2048 + b*128 + (tid-128)] / sum_amino;
    val = lrelu(lrelu(val));
    val *= params[P_PRED_W + tid];
    #pragma unroll
    for (int m = 32; m; m >>= 1) val += __shfl_xor(val, m, 64);
    if ((tid & 63) == 0) red[tid >> 6] = val;
    __syncthreads();
    if (tid == 0) out[b] = red[0]+red[1]+red[2]+red[3] + params[P_PRED_B];
}

// ---------------------------------------------------------------------------
extern "C" void kernel_launch(void* const* d_in, const int* in_sizes, int n_in,
                              void* d_out, int out_size, void* d_ws, size_t ws_size,
                              hipStream_t stream)
{
    const int* atoms     = (const int*)d_in[0];
    const int* adjacency = (const int*)d_in[2];
    const int* amino     = (const int*)d_in[3];
    float* out = (float*)d_out;                  // reference output dtype = f32
    (void)in_sizes; (void)n_in; (void)ws_size;

    // ws layout: total ~12.9 MiB
    char* base = (char*)d_ws;
    float* params = (float*)(base + 0);          // 141167 f32 (565 KB)
    float* src1   = (float*)(base + 565248);     // 32768 f32
    float* dst1   = (float*)(base + 696320);     // 32768 f32
    float* src2   = (float*)(base + 827392);     // 8192 f32
    float* dst2   = (float*)(base + 860160);     // 8192 f32
    float* acc    = (float*)(base + 892928);     // 4096 f32 (comp | prot)
    bf16*  A      = (bf16*)(base + 909568);      // 2,097,152 bf16
    bf16*  B      = (bf16*)(base + 5103872);     // 2,097,152 bf16
    bf16*  C      = (bf16*)(base + 9298176);     // 2,097,152 bf16

    bf16* Wh1 = B;                 // [n][256]
    bf16* multi = C;
    bf16* Wh2 = B;                 // [n][128] (Wh1 dead)
    bf16* xbuf = B + 1048576;
    bf16* atoms_vec = C;           // multi dead

    hipMemsetAsync(acc, 0, 4096*sizeof(float), stream);

    // parameter conversion (2 launches, per-tensor dtype detection)
    k_prep_a<<<420, 256, 0, stream>>>(d_in[1], d_in[4], d_in[5], d_in[6],
                                      d_in[7], d_in[8], d_in[9], d_in[10], params);
    k_prep_b<<<132, 256, 0, stream>>>(d_in[11], d_in[12], d_in[13], d_in[14],
                                      d_in[15], d_in[16], d_in[17], d_in[18], params);

    // protein conv chain (8 rows/block)
    k_conv_b<<<2048, 256, 0, stream>>>(nullptr, amino, params, A, 0, 1);
    k_conv_b<<<2048, 256, 0, stream>>>(A,       amino, params, B, 1, 0);
    k_conv_b<<<2048, 256, 0, stream>>>(B,       amino, params, A, 2, 0);  // A = amino_vec

    // GAT layer 1 (8 rows/block pre; 4 heads x 8 rows att)
    k_gat1_pre_b<<<1024, 256, 0, stream>>>(atoms, params, Wh1, src1, dst1);
    k_gat1_att_b<<<1024, 256, 0, stream>>>(adjacency, Wh1, src1, dst1, multi);

    // GAT layer 2 (8 rows/block)
    k_gat2_pre_b<<<1024, 128, 0, stream>>>(multi, params, Wh2, src2, dst2);
    k_gat2_att_b<<<1024, 256, 0, stream>>>(adjacency, Wh2, src2, dst2, xbuf);

    // atoms_vec = leaky(x @ W_comp^T + b)   (tiled, W in LDS)
    k_rowmat_tile<<<256, 256, 0, stream>>>(xbuf, params + P_W_COMP_W,
                                           params + P_W_COMP_B, atoms_vec);

    // masked attention-pool accumulations (tiled, W in LDS)
    k_att_acc_tile<<<256, 256, 0, stream>>>(atoms_vec, params + P_W_ATT_W,
                                            params + P_W_ATT_B, params + P_ATOMS_MASK,
                                            acc, 512);
    k_att_acc_tile<<<512, 256, 0, stream>>>(A, params + P_W_ATT_W,
                                            params + P_W_ATT_B, params + P_AMINO_MASK,
                                            acc + 2048, 1024);

    // head (float32 output)
    k_final<<<16, 256, 0, stream>>>(params, acc, out);
}

// Round 16
// 498.705 us; speedup vs baseline: 1.0797x; 1.0797x over previous
//
#include <hip/hip_runtime.h>
#include <hip/hip_bf16.h>

typedef __hip_bfloat16 bf16;

#define ALPHA 0.2f
#define NEGV  -9.0e15f
#define TI 8

__device__ __forceinline__ float b2f(bf16 x){ return __bfloat162float(x); }
__device__ __forceinline__ bf16  f2b(float x){ return __float2bfloat16(x); }
__device__ __forceinline__ float lrelu(float x){ return x > 0.f ? x : ALPHA*x; }
__device__ __forceinline__ float eluf(float x){ return x > 0.f ? x : expm1f(x); }

// ---------------- params block offsets (f32 elements) ----------------------
#define P_ATOMS_MASK 0
#define P_AMINO_MASK 8192
#define P_E_ATOM     24576
#define P_E_AMINO    37376
#define P_W_GAT      41216
#define P_A_GAT      73984
#define P_W_GO       74496
#define P_A_GO       107264
#define P_W_COMP_W   107520
#define P_W_COMP_B   123904
#define P_CONV_W     124032
#define P_CONV_B     124395
#define P_W_ATT_W    124398
#define P_W_ATT_B    140782
#define P_PRED_W     140910
#define P_PRED_B     141166
#define P_TOTAL      141167

__device__ __forceinline__ int detect_f32(const unsigned short* u, int n)
{
    int lim = n < 64 ? n : 64;
    bool f32like = false;
    for (int i = 0; i < lim; i += 2) {
        unsigned short h = u[i];
        int e = (h >> 7) & 0xFF;
        bool z = (h & 0x7FFF) == 0;
        if (!(z || (e >= 0x66 && e <= 0x88))) f32like = true;
    }
    if (!f32like && lim > 1 && (u[0] & 0x7FFF) == 0 && (u[1] & 0x7FFF) != 0)
        f32like = true;
    return f32like ? 1 : 0;
}
__device__ __forceinline__ float cvt_elem(const void* src, int e, int mode)
{
    return mode ? ((const float*)src)[e] : b2f(((const bf16*)src)[e]);
}

// Convert all 16 float tensors -> f32 params (per-tensor dtype detection).
__global__ __launch_bounds__(256) void k_prep(
    const void* p0, const void* p1, const void* p2, const void* p3,
    const void* p4, const void* p5, const void* p6, const void* p7,
    const void* p8, const void* p9, const void* p10, const void* p11,
    const void* p12, const void* p13, const void* p14, const void* p15,
    float* __restrict__ params)
{
    const void* ps[16] = {p0,p1,p2,p3,p4,p5,p6,p7,p8,p9,p10,p11,p12,p13,p14,p15};
    const int offs[17] = {0,8192,24576,37376,41216,73984,74496,107264,107520,
                          123904,124032,124395,124398,140782,140910,141166,P_TOTAL};
    int idx = blockIdx.x*256 + threadIdx.x;
    if (idx >= P_TOTAL) return;
    int k = 0;
    while (idx >= offs[k+1]) ++k;
    int mode = detect_f32((const unsigned short*)ps[k], offs[k+1]-offs[k]);
    params[idx] = cvt_elem(ps[k], idx - offs[k], mode);
}

// ---------------------------------------------------------------------------
// GAT layer 1 pre, 8 rows/block: av[k][r] in LDS; one W-load feeds 8 FMAs.
__global__ __launch_bounds__(256) void k_gat1_pre_b(
    const int* __restrict__ atoms, const float* __restrict__ params,
    bf16* __restrict__ Wh1, float* __restrict__ src1, float* __restrict__ dst1)
{
    int bid = blockIdx.x;              // b*64 + t
    int b = bid >> 6, n0 = (bid & 63) * 8;
    int tid = threadIdx.x;
    __shared__ float av[128][8];       // [k][r]
    __shared__ int aidx[8];
    if (tid < 8) aidx[tid] = atoms[b*512 + n0 + tid];
    __syncthreads();
    for (int idx = tid; idx < 1024; idx += 256) {
        int k = idx >> 3, r = idx & 7;
        av[k][r] = params[P_E_ATOM + aidx[r]*128 + k];
    }
    __syncthreads();
    int h = tid >> 6, f = tid & 63;
    const float* Wp = params + P_W_GAT + h*8192 + f;     // W_gat[h][k][f]
    float acc[8];
    #pragma unroll
    for (int r = 0; r < 8; ++r) acc[r] = 0.f;
    for (int k = 0; k < 128; ++k) {
        float w = Wp[k*64];
        #pragma unroll
        for (int r = 0; r < 8; ++r) acc[r] += av[k][r] * w;
    }
    float a1 = params[P_A_GAT + h*128 + f];
    float a2 = params[P_A_GAT + h*128 + 64 + f];
    #pragma unroll
    for (int r = 0; r < 8; ++r) {
        int n = n0 + r;
        Wh1[(size_t)(b*512 + n)*256 + h*64 + f] = f2b(acc[r]);
        float p1 = acc[r] * a1;
        float p2 = acc[r] * a2;
        #pragma unroll
        for (int m = 32; m; m >>= 1) { p1 += __shfl_xor(p1, m, 64); p2 += __shfl_xor(p2, m, 64); }
        if (f == 0) { src1[(b*4+h)*512 + n] = p1; dst1[(b*4+h)*512 + n] = p2; }
    }
}

// ---------------------------------------------------------------------------
// GAT layer 1 attention, 4 heads x TI=8 rows per block.
// att stored TRANSPOSED [h][j][ti]: phase-2 reads are 2 broadcast b128 per j.
__global__ __launch_bounds__(256) void k_gat1_att_b(
    const int* __restrict__ adj, const bf16* __restrict__ Wh1,
    const float* __restrict__ src1, const float* __restrict__ dst1,
    bf16* __restrict__ multi)
{
    int bid = blockIdx.x;              // b*64 + it
    int b = bid >> 6, i0 = (bid & 63) * TI;
    int tid = threadIdx.x;
    int h = tid >> 6, lane = tid & 63;
    __shared__ float att[4][512][TI];  // [h][j][ti], 64 KB
    const float* dstp = dst1 + (b*4+h)*512;
    float invr[TI];
    #pragma unroll
    for (int ti = 0; ti < TI; ++ti) {
        int i = i0 + ti;
        const int* adjrow = adj + ((size_t)(b*512 + i))*512;
        float s_i = src1[(b*4+h)*512 + i];
        float e[8];
        float lm = -3.0e38f;
        #pragma unroll
        for (int jj = 0; jj < 8; ++jj) {
            int j = lane + jj*64;
            float v = lrelu(s_i + dstp[j]);
            v = adjrow[j] > 0 ? v : NEGV;
            e[jj] = v;
            lm = fmaxf(lm, v);
        }
        #pragma unroll
        for (int m = 32; m; m >>= 1) lm = fmaxf(lm, __shfl_xor(lm, m, 64));
        float ls = 0.f;
        #pragma unroll
        for (int jj = 0; jj < 8; ++jj) {
            float ex = __expf(e[jj] - lm);
            att[h][lane + jj*64][ti] = ex;
            ls += ex;
        }
        #pragma unroll
        for (int m = 32; m; m >>= 1) ls += __shfl_xor(ls, m, 64);
        invr[ti] = 1.f / ls;           // butterfly leaves total in every lane
    }
    // phase 2 (same wave wrote att[h] -> wave-coherent, no block barrier)
    const bf16* Whp = Wh1 + (size_t)(b*512)*256 + h*64 + lane;
    float acc[TI];
    #pragma unroll
    for (int ti = 0; ti < TI; ++ti) acc[ti] = 0.f;
    const float4* ap = (const float4*)(&att[h][0][0]);
    for (int j = 0; j < 512; ++j) {
        float w = b2f(Whp[(size_t)j*256]);   // lanes coalesced: 128 B / wave
        float4 lo = ap[2*j];                 // broadcast (same addr all lanes)
        float4 hi = ap[2*j + 1];
        acc[0] += lo.x*w; acc[1] += lo.y*w; acc[2] += lo.z*w; acc[3] += lo.w*w;
        acc[4] += hi.x*w; acc[5] += hi.y*w; acc[6] += hi.z*w; acc[7] += hi.w*w;
    }
    #pragma unroll
    for (int ti = 0; ti < TI; ++ti) {
        float hp = acc[ti] * invr[ti];
        multi[(size_t)(b*512 + i0 + ti)*256 + h*64 + lane] = f2b(eluf(hp));
    }
}

// ---------------------------------------------------------------------------
// GAT layer 2 pre, 8 rows/block: row[k][r] in LDS; W_go read once per block.
__global__ __launch_bounds__(128) void k_gat2_pre_b(
    const bf16* __restrict__ multi, const float* __restrict__ params,
    bf16* __restrict__ Wh2, float* __restrict__ src2, float* __restrict__ dst2)
{
    int bid = blockIdx.x;              // b*64 + t
    int b = bid >> 6, n0 = (bid & 63) * 8;
    int tid = threadIdx.x;
    __shared__ float row[256][8];      // [k][r]
    __shared__ float sr[2][2][8];
    for (int idx = tid; idx < 2048; idx += 128) {
        int k = idx >> 3, r = idx & 7;
        row[k][r] = b2f(multi[(size_t)(b*512 + n0 + r)*256 + k]);
    }
    __syncthreads();
    const float* Wp = params + P_W_GO;
    float acc[8];
    #pragma unroll
    for (int r = 0; r < 8; ++r) acc[r] = 0.f;
    for (int k = 0; k < 256; ++k) {
        float w = Wp[k*128 + tid];
        #pragma unroll
        for (int r = 0; r < 8; ++r) acc[r] += row[k][r] * w;
    }
    float a1 = params[P_A_GO + tid];
    float a2 = params[P_A_GO + 128 + tid];
    int wid = tid >> 6;
    #pragma unroll
    for (int r = 0; r < 8; ++r) {
        Wh2[(size_t)(b*512 + n0 + r)*128 + tid] = f2b(acc[r]);
        float p1 = acc[r] * a1;
        float p2 = acc[r] * a2;
        #pragma unroll
        for (int m = 32; m; m >>= 1) { p1 += __shfl_xor(p1, m, 64); p2 += __shfl_xor(p2, m, 64); }
        if ((tid & 63) == 0) { sr[wid][0][r] = p1; sr[wid][1][r] = p2; }
    }
    __syncthreads();
    if (tid < 8)              src2[b*512 + n0 + tid]       = sr[0][0][tid] + sr[1][0][tid];
    else if (tid < 16)        dst2[b*512 + n0 + (tid-8)]   = sr[0][1][tid-8] + sr[1][1][tid-8];
}

// ---------------------------------------------------------------------------
// GAT layer 2 attention, TI=8 rows per block; att transposed [j][ti].
__global__ __launch_bounds__(256) void k_gat2_att_b(
    const int* __restrict__ adj, const bf16* __restrict__ Wh2,
    const float* __restrict__ src2, const float* __restrict__ dst2,
    bf16* __restrict__ x)
{
    int bid = blockIdx.x;              // b*64 + it
    int b = bid >> 6, i0 = (bid & 63) * TI;
    int tid = threadIdx.x;
    int wv = tid >> 6, lane = tid & 63;
    __shared__ float att[512][TI];     // [j][ti], 16 KB
    __shared__ float red[TI][256];     // 8 KB
    __shared__ float invs[TI];
    const float* dstp = dst2 + b*512;
    for (int ti = wv; ti < TI; ti += 4) {
        int i = i0 + ti;
        const int* adjrow = adj + ((size_t)(b*512 + i))*512;
        float s_i = src2[b*512 + i];
        float e[8];
        float lm = -3.0e38f;
        #pragma unroll
        for (int jj = 0; jj < 8; ++jj) {
            int j = lane + jj*64;
            float v = lrelu(s_i + dstp[j]);
            v = adjrow[j] > 0 ? v : NEGV;
            e[jj] = v;
            lm = fmaxf(lm, v);
        }
        #pragma unroll
        for (int m = 32; m; m >>= 1) lm = fmaxf(lm, __shfl_xor(lm, m, 64));
        float ls = 0.f;
        #pragma unroll
        for (int jj = 0; jj < 8; ++jj) {
            float ex = __expf(e[jj] - lm);
            att[lane + jj*64][ti] = ex;
            ls += ex;
        }
        #pragma unroll
        for (int m = 32; m; m >>= 1) ls += __shfl_xor(ls, m, 64);
        if (lane == 0) invs[ti] = 1.f / ls;
    }
    __syncthreads();
    int f = tid & 127, c = tid >> 7;
    const bf16* Whp = Wh2 + (size_t)(b*512)*128 + f;
    float acc[TI];
    #pragma unroll
    for (int ti = 0; ti < TI; ++ti) acc[ti] = 0.f;
    const float4* ap = (const float4*)(&att[0][0]);
    int j0 = c * 256;
    for (int j = j0; j < j0 + 256; ++j) {
        float w = b2f(Whp[(size_t)j*128]);
        float4 lo = ap[2*j];
        float4 hi = ap[2*j + 1];
        acc[0] += lo.x*w; acc[1] += lo.y*w; acc[2] += lo.z*w; acc[3] += lo.w*w;
        acc[4] += hi.x*w; acc[5] += hi.y*w; acc[6] += hi.z*w; acc[7] += hi.w*w;
    }
    #pragma unroll
    for (int ti = 0; ti < TI; ++ti) red[ti][tid] = acc[ti];
    __syncthreads();
    if (c == 0) {
        #pragma unroll
        for (int ti = 0; ti < TI; ++ti) {
            float hp = (red[ti][f] + red[ti][f+128]) * invs[ti];
            x[(size_t)(b*512 + i0 + ti)*128 + f] = f2b(eluf(hp));
        }
    }
}

// ---------------------------------------------------------------------------
// Tiled row-matvec: out[r][l] = lrelu(in[r][:] . W[l][:] + bias[l]).
#define RM_ROWS 32
__global__ __launch_bounds__(256) void k_rowmat_tile(
    const bf16* __restrict__ in, const float* __restrict__ W,
    const float* __restrict__ bias, bf16* __restrict__ outv)
{
    __shared__ float wlds[128*129];
    __shared__ float rlds[RM_ROWS][128];
    int tid = threadIdx.x;
    size_t row0 = (size_t)blockIdx.x * RM_ROWS;
    for (int idx = tid; idx < 16384; idx += 256)
        wlds[(idx >> 7)*129 + (idx & 127)] = W[idx];
    for (int idx = tid; idx < RM_ROWS*128; idx += 256)
        rlds[idx >> 7][idx & 127] = b2f(in[row0*128 + idx]);
    __syncthreads();
    int l = tid & 127, g = tid >> 7;
    float bl = bias[l];
    #pragma unroll
    for (int rg = 0; rg < 16; rg += 4) {
        int r0 = 2*rg + g;
        float a0=0.f, a1=0.f, a2=0.f, a3=0.f;
        for (int k = 0; k < 128; ++k) {
            float w = wlds[l*129 + k];
            a0 += rlds[r0][k]*w;   a1 += rlds[r0+2][k]*w;
            a2 += rlds[r0+4][k]*w; a3 += rlds[r0+6][k]*w;
        }
        outv[(row0 + r0  )*128 + l] = f2b(lrelu(a0+bl));
        outv[(row0 + r0+2)*128 + l] = f2b(lrelu(a1+bl));
        outv[(row0 + r0+4)*128 + l] = f2b(lrelu(a2+bl));
        outv[(row0 + r0+6)*128 + l] = f2b(lrelu(a3+bl));
    }
}

// ---------------------------------------------------------------------------
// Tiled masked att-pool; one atomicAdd per l per block.
__global__ __launch_bounds__(256) void k_att_acc_tile(
    const bf16* __restrict__ in, const float* __restrict__ W,
    const float* __restrict__ bias, const float* __restrict__ mask,
    float* __restrict__ acc, int per_b)
{
    __shared__ float wlds[128*129];
    __shared__ float rlds[RM_ROWS][128];
    __shared__ float mlds[RM_ROWS];
    __shared__ float psum[128];
    int tid = threadIdx.x;
    size_t row0 = (size_t)blockIdx.x * RM_ROWS;
    int b = (int)(row0 / per_b);
    for (int idx = tid; idx < 16384; idx += 256)
        wlds[(idx >> 7)*129 + (idx & 127)] = W[idx];
    for (int idx = tid; idx < RM_ROWS*128; idx += 256)
        rlds[idx >> 7][idx & 127] = b2f(in[row0*128 + idx]);
    if (tid < RM_ROWS) mlds[tid] = mask[row0 + tid];
    __syncthreads();
    int l = tid & 127, g = tid >> 7;
    float bl = bias[l];
    float vsum = 0.f;
    #pragma unroll
    for (int rg = 0; rg < 16; rg += 4) {
        int r0 = 2*rg + g;
        float a0=0.f, a1=0.f, a2=0.f, a3=0.f;
        for (int k = 0; k < 128; ++k) {
            float w = wlds[l*129 + k];
            a0 += rlds[r0][k]*w;   a1 += rlds[r0+2][k]*w;
            a2 += rlds[r0+4][k]*w; a3 += rlds[r0+6][k]*w;
        }
        vsum += lrelu(a0+bl)*mlds[r0]   + lrelu(a1+bl)*mlds[r0+2]
              + lrelu(a2+bl)*mlds[r0+4] + lrelu(a3+bl)*mlds[r0+6];
    }
    if (g == 1) psum[l] = vsum;
    __syncthreads();
    if (g == 0) atomicAdd(&acc[b*128 + l], vsum + psum[l]);
}

// ---------------------------------------------------------------------------
// 11x11 SAME conv, 8 output rows per block (tile 18x138 staged once).
__global__ __launch_bounds__(256) void k_conv_b(
    const bf16* __restrict__ in, const int* __restrict__ amino,
    const float* __restrict__ params, bf16* __restrict__ out,
    int layer, int first)
{
    int bid = blockIdx.x;              // b*128 + t
    int b = bid >> 7, i0 = (bid & 127) * 8;
    int tid = threadIdx.x;
    __shared__ float tile[18][139];
    __shared__ float wts[121];
    __shared__ float bias;
    __shared__ int amn[18];
    if (tid < 121) wts[tid] = params[P_CONV_W + layer*121 + tid];
    if (tid == 121) bias = params[P_CONV_B + layer];
    if (first && tid < 18) {
        int ri = i0 + tid - 5;
        amn[tid] = (ri >= 0 && ri < 1024) ? amino[b*1024 + ri] : 0;
    }
    __syncthreads();
    for (int idx = tid; idx < 18*138; idx += 256) {
        int r = idx / 138, cc = idx % 138;
        int ri = i0 + r - 5, cj = cc - 5;
        float v = 0.f;
        if (ri >= 0 && ri < 1024 && cj >= 0 && cj < 128) {
            v = first ? params[P_E_AMINO + amn[r]*128 + cj]
                      : b2f(in[((size_t)(b*1024 + ri))*128 + cj]);
        }
        tile[r][cc] = v;
    }
    __syncthreads();
    int c = tid & 127, g = tid >> 7;
    #pragma unroll
    for (int rg = 0; rg < 4; ++rg) {
        int ro = rg*2 + g;
        float a = bias;
        #pragma unroll
        for (int di = 0; di < 11; ++di)
            #pragma unroll
            for (int dj = 0; dj < 11; ++dj)
                a += tile[ro + di][c + dj] * wts[di*11 + dj];
        out[(size_t)(b*1024 + i0 + ro)*128 + c] = f2b(fmaxf(a, 0.f));
    }
}

// ---------------------------------------------------------------------------
// final: mask means, leaky x2, pred dot.  block per b.  OUTPUT IS FLOAT32.
__global__ __launch_bounds__(256) void k_final(
    const float* __restrict__ params, const float* __restrict__ acc,
    float* __restrict__ out)
{
    int b = blockIdx.x, tid = threadIdx.x;
    __shared__ float red[256];
    float s = 0.f;
    for (int t = tid; t < 512; t += 256) s += params[P_ATOMS_MASK + b*512 + t];
    #pragma unroll
    for (int m = 32; m; m >>= 1) s += __shfl_xor(s, m, 64);
    if ((tid & 63) == 0) red[tid >> 6] = s;
    __syncthreads();
    float sum_atoms = red[0]+red[1]+red[2]+red[3];
    __syncthreads();
    s = 0.f;
    for (int t = tid; t < 1024; t += 256) s += params[P_AMINO_MASK + b*1024 + t];
    #pragma unroll
    for (int m = 32; m; m >>= 1) s += __shfl_xor(s, m, 64);
    if ((tid & 63) == 0) red[tid >> 6] = s;
    __syncthreads();
    float sum_amino = red[0]+red[1]+red[2]+red[3];
    __syncthreads();
    float val = (tid < 128) ? acc[b*128 + tid] / sum_atoms
                            : acc[2048 + b*128 + (tid-128)] / sum_amino;
    val = lrelu(lrelu(val));
    val *= params[P_PRED_W + tid];
    #pragma unroll
    for (int m = 32; m; m >>= 1) val += __shfl_xor(val, m, 64);
    if ((tid & 63) == 0) red[tid >> 6] = val;
    __syncthreads();
    if (tid == 0) out[b] = red[0]+red[1]+red[2]+red[3] + params[P_PRED_B];
}

// ---------------------------------------------------------------------------
extern "C" void kernel_launch(void* const* d_in, const int* in_sizes, int n_in,
                              void* d_out, int out_size, void* d_ws, size_t ws_size,
                              hipStream_t stream)
{
    const int* atoms     = (const int*)d_in[0];
    const int* adjacency = (const int*)d_in[2];
    const int* amino     = (const int*)d_in[3];
    float* out = (float*)d_out;                  // reference output dtype = f32
    (void)in_sizes; (void)n_in; (void)ws_size;

    // ws layout: total ~12.9 MiB
    char* base = (char*)d_ws;
    float* params = (float*)(base + 0);          // 141167 f32 (565 KB)
    float* src1   = (float*)(base + 565248);     // 32768 f32
    float* dst1   = (float*)(base + 696320);     // 32768 f32
    float* src2   = (float*)(base + 827392);     // 8192 f32
    float* dst2   = (float*)(base + 860160);     // 8192 f32
    float* acc    = (float*)(base + 892928);     // 4096 f32 (comp | prot)
    bf16*  A      = (bf16*)(base + 909568);      // 2,097,152 bf16
    bf16*  B      = (bf16*)(base + 5103872);     // 2,097,152 bf16
    bf16*  C      = (bf16*)(base + 9298176);     // 2,097,152 bf16

    bf16* Wh1 = B;                 // [n][256]
    bf16* multi = C;
    bf16* Wh2 = B;                 // [n][128] (Wh1 dead)
    bf16* xbuf = B + 1048576;
    bf16* atoms_vec = C;           // multi dead

    hipMemsetAsync(acc, 0, 4096*sizeof(float), stream);

    // parameter conversion (1 launch, per-tensor dtype detection)
    k_prep<<<552, 256, 0, stream>>>(d_in[1], d_in[4], d_in[5], d_in[6],
                                    d_in[7], d_in[8], d_in[9], d_in[10],
                                    d_in[11], d_in[12], d_in[13], d_in[14],
                                    d_in[15], d_in[16], d_in[17], d_in[18], params);

    // protein conv chain (8 rows/block)
    k_conv_b<<<2048, 256, 0, stream>>>(nullptr, amino, params, A, 0, 1);
    k_conv_b<<<2048, 256, 0, stream>>>(A,       amino, params, B, 1, 0);
    k_conv_b<<<2048, 256, 0, stream>>>(B,       amino, params, A, 2, 0);  // A = amino_vec

    // GAT layer 1 (8 rows/block pre; 4 heads x 8 rows att, transposed att)
    k_gat1_pre_b<<<1024, 256, 0, stream>>>(atoms, params, Wh1, src1, dst1);
    k_gat1_att_b<<<1024, 256, 0, stream>>>(adjacency, Wh1, src1, dst1, multi);

    // GAT layer 2 (8 rows/block, transposed att)
    k_gat2_pre_b<<<1024, 128, 0, stream>>>(multi, params, Wh2, src2, dst2);
    k_gat2_att_b<<<1024, 256, 0, stream>>>(adjacency, Wh2, src2, dst2, xbuf);

    // atoms_vec = leaky(x @ W_comp^T + b)   (tiled, W in LDS)
    k_rowmat_tile<<<256, 256, 0, stream>>>(xbuf, params + P_W_COMP_W,
                                           params + P_W_COMP_B, atoms_vec);

    // masked attention-pool accumulations (tiled, W in LDS)
    k_att_acc_tile<<<256, 256, 0, stream>>>(atoms_vec, params + P_W_ATT_W,
                                            params + P_W_ATT_B, params + P_ATOMS_MASK,
                                            acc, 512);
    k_att_acc_tile<<<512, 256, 0, stream>>>(A, params + P_W_ATT_W,
                                            params + P_W_ATT_B, params + P_AMINO_MASK,
                                            acc + 2048, 1024);

    // head (float32 output)
    k_final<<<16, 256, 0, stream>>>(params, acc, out);
}